// Round 6
// baseline (314.396 us; speedup 1.0000x reference)
//
#include <hip/hip_runtime.h>

#define BN_EPS 1e-5f

typedef unsigned short u16;
typedef __bf16 bf16x8 __attribute__((ext_vector_type(8)));
typedef float floatx4 __attribute__((ext_vector_type(4)));
typedef u16 u16x4 __attribute__((ext_vector_type(4)));
typedef u16 u16x8 __attribute__((ext_vector_type(8)));

__device__ __forceinline__ u16 f2bf(float f) {
    union { float f; unsigned int u; } v; v.f = f;
    unsigned int r = (v.u + 0x7fffu + ((v.u >> 16) & 1u)) >> 16;
    return (u16)r;
}

// packed f32x2 -> bf16x2 (RNE), one VALU op
__device__ __forceinline__ unsigned int cvtpk(float lo, float hi) {
    unsigned int r;
    asm("v_cvt_pk_bf16_f32 %0, %1, %2" : "=v"(r) : "v"(lo), "v"(hi));
    return r;
}

// async 16B global->LDS; lane i lands at (wave-uniform) dst + i*16.
__device__ __forceinline__ void gld16(const void* gsrc, void* ldst) {
    __builtin_amdgcn_global_load_lds(
        (const __attribute__((address_space(1))) unsigned int*)gsrc,
        (__attribute__((address_space(3))) unsigned int*)ldst, 16, 0, 0);
}

// additive seg swizzle for transpose-staged [row][64] u16 tiles
__device__ __forceinline__ int addsw(int seg, int s) {
    return (seg + (s & 7) + ((s >> 3) & 7)) & 7;
}

// ---------------------------------------------------------------- prep ----
__global__ __launch_bounds__(256) void prep_kernel(
    const float* __restrict__ wt, const float* __restrict__ wp,
    const float* __restrict__ wg, const float* __restrict__ wz,
    const float* __restrict__ g1, const float* __restrict__ b1,
    const float* __restrict__ m1, const float* __restrict__ v1,
    const float* __restrict__ g2, const float* __restrict__ b2,
    const float* __restrict__ m2, const float* __restrict__ v2,
    const float* __restrict__ g3, const float* __restrict__ b3,
    const float* __restrict__ m3, const float* __restrict__ v3,
    const float* __restrict__ g4, const float* __restrict__ b4,
    const float* __restrict__ m4, const float* __restrict__ v4,
    u16* __restrict__ W1bf, float* __restrict__ shift1,
    u16* __restrict__ Wzbf, float* __restrict__ shift4)
{
    int id = blockIdx.x * 256 + threadIdx.x;
    if (id < 384 * 256) {
        int r = id >> 8, c = id & 255;
        int grp = r >> 7, ch = r & 127;
        const float* wsrc = grp == 0 ? wt : (grp == 1 ? wp : wg);
        const float* gg = grp == 0 ? g1 : (grp == 1 ? g2 : g3);
        const float* bb = grp == 0 ? b1 : (grp == 1 ? b2 : b3);
        const float* mm = grp == 0 ? m1 : (grp == 1 ? m2 : m3);
        const float* vv = grp == 0 ? v1 : (grp == 1 ? v2 : v3);
        float scale = gg[ch] * rsqrtf(vv[ch] + BN_EPS);
        W1bf[id] = f2bf(wsrc[ch * 256 + c] * scale);
        if (c == 0) shift1[r] = bb[ch] - mm[ch] * scale;
    }
    if (id < 256 * 128) {
        int o = id >> 7;
        float scale = g4[o] * rsqrtf(v4[o] + BN_EPS);
        Wzbf[id] = f2bf(wz[id] * scale);
        if ((id & 127) == 0) shift4[o] = b4[o] - m4[o] * scale;
    }
}

// ------------------------------------------------------------ K1 = g1+g2 --
// One 128-pixel subtile per block (grid 32x16 = 512 blocks -> 2 blocks/CU).
// 64 KB LDS pool: GEMM phase = A(48K)+B(16K); then the SAME pool becomes the
// 4 phi/g tiles (64K) for the KV phase (A/B are dead after the last barrier).
// theta -> HBM; KV partial -> partials[n][sk].
__global__ __launch_bounds__(512, 4) void k1_kernel(
    const float* __restrict__ x, const u16* __restrict__ W1,
    const float* __restrict__ shift1,
    u16* __restrict__ theta_sm, float* __restrict__ partials)
{
    const int sk = blockIdx.x, n = blockIdx.y;   // sk 0..31
    const int tid = threadIdx.x;
    const int w = tid >> 6, lane = tid & 63;
    const int quad = lane >> 4, l16 = lane & 15;

    __shared__ __align__(16) u16 pool[32768];    // 64 KB
    u16* ldsA = pool;                            // 384*64 (48 KB)
    u16* ldsB = pool + 24576;                    // 128*64 (16 KB)
    // KV phase: tile t at pool + t*8192  (phiL, phiH, gL, gH)

    floatx4 acc[3][8];
#pragma unroll
    for (int i = 0; i < 3; ++i)
#pragma unroll
        for (int j = 0; j < 8; ++j) acc[i][j] = floatx4{0.f, 0.f, 0.f, 0.f};

    const int cp = w * 4 + quad;   // channel pair 0..31
    const float* xb = x + ((size_t)n * 256 + 2 * cp) * 4096 + sk * 128;
    unsigned int* ldsBdw = (unsigned int*)ldsB;

    float4 xv[2][2];               // single prefetch buffer (16 VGPR)

    auto loadx = [&](int kc) {
#pragma unroll
        for (int ch = 0; ch < 2; ++ch)
#pragma unroll
            for (int hb = 0; hb < 2; ++hb)
                xv[ch][hb] = *((const float4*)(xb + (size_t)(kc * 64 + ch) * 4096) + hb * 16 + l16);
    };
    auto writeB = [&]() {
#pragma unroll
        for (int hb = 0; hb < 2; ++hb)
#pragma unroll
            for (int j = 0; j < 4; ++j) {
                int s = hb * 64 + l16 * 4 + j;
                ldsBdw[s * 32 + addsw(w, s) * 4 + quad] =
                    cvtpk(((const float*)&xv[0][hb])[j], ((const float*)&xv[1][hb])[j]);
            }
    };
    auto stageA = [&](int kc) {
#pragma unroll
        for (int i = 0; i < 6; ++i) {
            int op = w * 6 + i;
            int r = op * 8 + (lane >> 3);
            int lseg = (lane & 7) ^ (r & 7);
            gld16(W1 + (size_t)r * 256 + kc * 64 + lseg * 8, ldsA + op * 512);
        }
    };

    loadx(0);
    for (int kc = 0; kc < 4; ++kc) {
        writeB();
        if (kc < 3) loadx(kc + 1);   // refill xv; consumed next iter (post-barrier)
        stageA(kc);
        __syncthreads();
#pragma unroll
        for (int kk = 0; kk < 2; ++kk) {
            bf16x8 a[3];
#pragma unroll
            for (int mt = 0; mt < 3; ++mt) {
                int r = mt * 128 + w * 16 + l16;
                int phys = (kk * 4 + quad) ^ (r & 7);
                a[mt] = *(const bf16x8*)(ldsA + r * 64 + phys * 8);
            }
#pragma unroll
            for (int ni = 0; ni < 8; ++ni) {
                int s = ni * 16 + l16;
                int phys = addsw(kk * 4 + quad, s);
                bf16x8 b = *(const bf16x8*)(ldsB + s * 64 + phys * 8);
#pragma unroll
                for (int mt = 0; mt < 3; ++mt)
                    acc[mt][ni] = __builtin_amdgcn_mfma_f32_16x16x32_bf16(
                        a[mt], b, acc[mt][ni], 0, 0, 0);
            }
        }
        __syncthreads();
    }

    const int ocq = w * 16 + quad * 4;
    // theta -> HBM (s-major [s][c], 8B stores)
    {
        float sh0 = shift1[ocq + 0], sh1 = shift1[ocq + 1];
        float sh2 = shift1[ocq + 2], sh3 = shift1[ocq + 3];
#pragma unroll
        for (int ni = 0; ni < 8; ++ni) {
            int s = sk * 128 + ni * 16 + l16;
            float v0 = acc[0][ni][0] + sh0, v1 = acc[0][ni][1] + sh1;
            float v2 = acc[0][ni][2] + sh2, v3 = acc[0][ni][3] + sh3;
            v0 = v0 > 0.f ? v0 : 0.f;
            v1 = v1 > 0.f ? v1 : 0.f;
            v2 = v2 > 0.f ? v2 : 0.f;
            v3 = v3 > 0.f ? v3 : 0.f;
            uint2 pk;
            pk.x = cvtpk(v0, v1);
            pk.y = cvtpk(v2, v3);
            *(uint2*)(theta_sm + (size_t)n * 524288 + (size_t)s * 128 + ocq) = pk;
        }
    }
    // phi (mt=1) -> tiles 0/1, g (mt=2) -> tiles 2/3 in the pool (A/B dead).
    // Rows [ch][64], xor seg swizzle phys = (s6>>3) ^ (ch&7).
#pragma unroll
    for (int mt = 1; mt < 3; ++mt)
#pragma unroll
        for (int r = 0; r < 4; ++r) {
            int ch = ocq + r;
            float sh = shift1[mt * 128 + ch];
#pragma unroll
            for (int ni = 0; ni < 8; ++ni) {
                int sl = ni * 16 + l16;
                int half = sl >> 6, s6 = sl & 63;
                int phys = (s6 >> 3) ^ (ch & 7);
                float val = acc[mt][ni][r] + sh;
                val = val > 0.f ? val : 0.f;
                pool[((mt - 1) * 2 + half) * 8192 + ch * 64 + phys * 8 + (s6 & 7)] = f2bf(val);
            }
        }
    __syncthreads();

    // KV[d][c] = sum_s g[d,s] * phi[c,s] over this block's 128 pixels
    floatx4 kv[8];
#pragma unroll
    for (int i = 0; i < 8; ++i) kv[i] = floatx4{0.f, 0.f, 0.f, 0.f};
#pragma unroll
    for (int h = 0; h < 2; ++h)
#pragma unroll
        for (int kk = 0; kk < 2; ++kk) {
            int rd = w * 16 + l16;
            int physa = (kk * 4 + quad) ^ (rd & 7);
            bf16x8 a = *(const bf16x8*)(pool + (2 + h) * 8192 + rd * 64 + physa * 8);
#pragma unroll
            for (int ci = 0; ci < 8; ++ci) {
                int rc = ci * 16 + l16;
                int physb = (kk * 4 + quad) ^ (rc & 7);
                bf16x8 b = *(const bf16x8*)(pool + h * 8192 + rc * 64 + physb * 8);
                kv[ci] = __builtin_amdgcn_mfma_f32_16x16x32_bf16(a, b, kv[ci], 0, 0, 0);
            }
        }

    float* outp = partials + (size_t)(n * 32 + sk) * 16384;
#pragma unroll
    for (int r = 0; r < 4; ++r) {
        int d = w * 16 + quad * 4 + r;
#pragma unroll
        for (int ci = 0; ci < 8; ++ci)
            outp[d * 128 + ci * 16 + l16] = kv[ci][r];
    }
}

// ----------------------------------------------------------- kv reduce ----
__global__ __launch_bounds__(256) void kv_reduce_kernel(
    const float* __restrict__ partials, u16* __restrict__ kvT)
{
    int n = blockIdx.y;
    int f4 = blockIdx.x * 256 + threadIdx.x;    // 0..4095
    const float4* p4 = (const float4*)partials;
    float4 s = {0.f, 0.f, 0.f, 0.f};
#pragma unroll
    for (int kc = 0; kc < 32; ++kc) {
        float4 v = p4[(size_t)(n * 32 + kc) * 4096 + f4];
        s.x += v.x; s.y += v.y; s.z += v.z; s.w += v.w;
    }
    u16x4 o; o[0] = f2bf(s.x); o[1] = f2bf(s.y); o[2] = f2bf(s.z); o[3] = f2bf(s.w);
    *(u16x4*)(kvT + (size_t)n * 16384 + f4 * 4) = o;
}

// ------------------------------------------------------------ K34 = g3+g4 -
// y[c2][s2 = st*128+j] = (theta @ kvT^T)[s = c2*32 + st][d = j]  (reshape!)
// 64 KB pool (2 blocks/CU): region A = TK buf0 / Wz chunks; region B = TK
// buf1, then Y[2][128][64].  out[o][st*128+j] = relu(Wz.y + shift4 + x).
__global__ __launch_bounds__(512, 4) void k34_kernel(
    const u16* __restrict__ theta_sm, const u16* __restrict__ kvT,
    const u16* __restrict__ Wz, const float* __restrict__ shift4,
    const float* __restrict__ x, float* __restrict__ out)
{
    const int st = blockIdx.x, n = blockIdx.y;   // st 0..31
    const int tid = threadIdx.x;
    const int w = tid >> 6, lane = tid & 63;
    const int quad = lane >> 4, l16 = lane & 15;

    __shared__ __align__(16) u16 pool[32768];    // 64 KB
    u16* Y = pool + 16384;                       // region B as Y

    // theta row c2 lives at tbase + c2*4096 (s = c2*32 + st)
    const u16* tbase = theta_sm + (size_t)n * 524288 + (size_t)st * 128;
    const u16* kbase = kvT + (size_t)n * 16384;

    floatx4 acc3[8];
#pragma unroll
    for (int i = 0; i < 8; ++i) acc3[i] = floatx4{0.f, 0.f, 0.f, 0.f};

    auto stageTK = [&](u16* T, u16* K, int ch) {
#pragma unroll
        for (int i = 0; i < 2; ++i) {
            int op = w * 2 + i;
            int r = op * 8 + (lane >> 3);       // = c2 for T, = d for K
            int lseg = (lane & 7) ^ (r & 7);
            gld16(tbase + (size_t)r * 4096 + ch * 64 + lseg * 8, T + op * 512);
            gld16(kbase + (size_t)r * 128 + ch * 64 + lseg * 8, K + op * 512);
        }
    };
    auto stageWz = [&](int ch) {                 // 256 o-rows x 64 c2 -> region A
#pragma unroll
        for (int i = 0; i < 4; ++i) {
            int op = w * 4 + i;
            int r = op * 8 + (lane >> 3);
            int lseg = (lane & 7) ^ (r & 7);
            gld16(Wz + (size_t)r * 128 + ch * 64 + lseg * 8, pool + op * 512);
        }
    };
    auto comp3 = [&](const u16* T, const u16* K) {
#pragma unroll
        for (int kk = 0; kk < 2; ++kk) {
            int rc2 = w * 16 + l16;
            int physa = (kk * 4 + quad) ^ (rc2 & 7);
            bf16x8 a = *(const bf16x8*)(T + rc2 * 64 + physa * 8);
#pragma unroll
            for (int di = 0; di < 8; ++di) {
                int rd = di * 16 + l16;
                int physb = (kk * 4 + quad) ^ (rd & 7);
                bf16x8 b = *(const bf16x8*)(K + rd * 64 + physb * 8);
                acc3[di] = __builtin_amdgcn_mfma_f32_16x16x32_bf16(a, b, acc3[di], 0, 0, 0);
            }
        }
    };

    stageTK(pool, pool + 8192, 0);               // TK0 -> region A
    __syncthreads();                             // b0
    stageTK(pool + 16384, pool + 24576, 1);      // TK1 -> region B
    comp3(pool, pool + 8192);
    __syncthreads();                             // b1 (A reads drained)
    stageWz(0);                                  // Wz ch0 -> region A (overlaps comp3 B)
    comp3(pool + 16384, pool + 24576);
    __syncthreads();                             // b2 (B reads + Wz staging drained)

    // acc3[di][r] = y_loc[c2 = w*16+quad*4+r][j = di*16+l16];
    // write TRANSPOSED into Y[half c2][j][c64], phys = (c64>>3)^(j&7).
#pragma unroll
    for (int di = 0; di < 8; ++di) {
        int j = di * 16 + l16;
#pragma unroll
        for (int r = 0; r < 4; ++r) {
            int c2 = w * 16 + quad * 4 + r;
            int half = c2 >> 6, c64 = c2 & 63;
            int phys = (c64 >> 3) ^ (j & 7);
            Y[half * 8192 + j * 64 + phys * 8 + (c64 & 7)] = f2bf(acc3[di][r]);
        }
    }
    __syncthreads();                             // b3 (Y visible)

    floatx4 acc4[2][8];
#pragma unroll
    for (int i = 0; i < 2; ++i)
#pragma unroll
        for (int j = 0; j < 8; ++j) acc4[i][j] = floatx4{0.f, 0.f, 0.f, 0.f};

    auto comp4 = [&](int ch) {                   // Wz chunk in region A
#pragma unroll
        for (int kk = 0; kk < 2; ++kk) {
            bf16x8 a[2];
#pragma unroll
            for (int mi = 0; mi < 2; ++mi) {
                int r = w * 32 + mi * 16 + l16;
                int phys = (kk * 4 + quad) ^ (r & 7);
                a[mi] = *(const bf16x8*)(pool + r * 64 + phys * 8);
            }
#pragma unroll
            for (int ni = 0; ni < 8; ++ni) {
                int s = ni * 16 + l16;          // j
                int phys = (kk * 4 + quad) ^ (s & 7);
                bf16x8 b = *(const bf16x8*)(Y + ch * 8192 + s * 64 + phys * 8);
#pragma unroll
                for (int mi = 0; mi < 2; ++mi)
                    acc4[mi][ni] = __builtin_amdgcn_mfma_f32_16x16x32_bf16(
                        a[mi], b, acc4[mi][ni], 0, 0, 0);
            }
        }
    };

    comp4(0);
    __syncthreads();                             // b4 (A reads drained)
    stageWz(1);
    __syncthreads();                             // b5
    comp4(1);

#pragma unroll
    for (int mi = 0; mi < 2; ++mi)
#pragma unroll
        for (int r = 0; r < 4; ++r) {
            int o = w * 32 + mi * 16 + quad * 4 + r;
            float sh = shift4[o];
#pragma unroll
            for (int ni = 0; ni < 8; ++ni) {
                int s2 = st * 128 + ni * 16 + l16;
                size_t idx = ((size_t)n * 256 + o) * 4096 + s2;
                float val = acc4[mi][ni][r] + sh + x[idx];
                out[idx] = val > 0.f ? val : 0.f;
            }
        }
}

// -------------------------------------------------------------- launch ----
extern "C" void kernel_launch(void* const* d_in, const int* in_sizes, int n_in,
                              void* d_out, int out_size, void* d_ws, size_t ws_size,
                              hipStream_t stream)
{
    const float* x  = (const float*)d_in[0];
    const float* wt = (const float*)d_in[1];
    const float* wp = (const float*)d_in[2];
    const float* wg = (const float*)d_in[3];
    const float* wz = (const float*)d_in[4];
    const float* bn[16];
    for (int i = 0; i < 16; ++i) bn[i] = (const float*)d_in[5 + i];

    char* ws = (char*)d_ws;
    u16*   W1bf     = (u16*)  (ws + 0);          // 196608
    float* shift1   = (float*)(ws + 196608);     // 1536
    u16*   Wzbf     = (u16*)  (ws + 198144);     // 65536
    float* shift4   = (float*)(ws + 263680);     // 1024
    u16*   theta_sm = (u16*)  (ws + 264704);     // 16*4096*128*2 = 16777216
    float* partials = (float*)(ws + 17041920);   // 16*32*16384*4 = 33554432
    u16*   kvT      = (u16*)  (ws + 50596352);   // 524288 (end ~51.1 MB)
    float* out = (float*)d_out;

    prep_kernel<<<384, 256, 0, stream>>>(
        wt, wp, wg, wz,
        bn[0], bn[1], bn[2], bn[3],
        bn[4], bn[5], bn[6], bn[7],
        bn[8], bn[9], bn[10], bn[11],
        bn[12], bn[13], bn[14], bn[15],
        W1bf, shift1, Wzbf, shift4);

    k1_kernel<<<dim3(32, 16), 512, 0, stream>>>(x, W1bf, shift1, theta_sm, partials);
    kv_reduce_kernel<<<dim3(16, 16), 256, 0, stream>>>(partials, kvT);
    k34_kernel<<<dim3(32, 16), 512, 0, stream>>>(theta_sm, kvT, Wzbf, shift4, x, out);
}

// Round 7
// 198.698 us; speedup vs baseline: 1.5823x; 1.5823x over previous
//
#include <hip/hip_runtime.h>

#define BN_EPS 1e-5f

typedef unsigned short u16;
typedef __bf16 bf16x8 __attribute__((ext_vector_type(8)));
typedef float floatx4 __attribute__((ext_vector_type(4)));
typedef u16 u16x4 __attribute__((ext_vector_type(4)));
typedef u16 u16x8 __attribute__((ext_vector_type(8)));

__device__ __forceinline__ u16 f2bf(float f) {
    union { float f; unsigned int u; } v; v.f = f;
    unsigned int r = (v.u + 0x7fffu + ((v.u >> 16) & 1u)) >> 16;
    return (u16)r;
}

// packed f32x2 -> bf16x2 (RNE), one VALU op
__device__ __forceinline__ unsigned int cvtpk(float lo, float hi) {
    unsigned int r;
    asm("v_cvt_pk_bf16_f32 %0, %1, %2" : "=v"(r) : "v"(lo), "v"(hi));
    return r;
}

// async 16B global->LDS; lane i lands at (wave-uniform) dst + i*16.
__device__ __forceinline__ void gld16(const void* gsrc, void* ldst) {
    __builtin_amdgcn_global_load_lds(
        (const __attribute__((address_space(1))) unsigned int*)gsrc,
        (__attribute__((address_space(3))) unsigned int*)ldst, 16, 0, 0);
}

// additive seg swizzle for transpose-staged [row][64] u16 tiles
__device__ __forceinline__ int addsw(int seg, int s) {
    return (seg + (s & 7) + ((s >> 3) & 7)) & 7;
}

// ---------------------------------------------------------------- prep ----
__global__ __launch_bounds__(256) void prep_kernel(
    const float* __restrict__ wt, const float* __restrict__ wp,
    const float* __restrict__ wg, const float* __restrict__ wz,
    const float* __restrict__ g1, const float* __restrict__ b1,
    const float* __restrict__ m1, const float* __restrict__ v1,
    const float* __restrict__ g2, const float* __restrict__ b2,
    const float* __restrict__ m2, const float* __restrict__ v2,
    const float* __restrict__ g3, const float* __restrict__ b3,
    const float* __restrict__ m3, const float* __restrict__ v3,
    const float* __restrict__ g4, const float* __restrict__ b4,
    const float* __restrict__ m4, const float* __restrict__ v4,
    u16* __restrict__ W1bf, float* __restrict__ shift1,
    u16* __restrict__ Wzbf, float* __restrict__ shift4)
{
    int id = blockIdx.x * 256 + threadIdx.x;
    if (id < 384 * 256) {
        int r = id >> 8, c = id & 255;
        int grp = r >> 7, ch = r & 127;
        const float* wsrc = grp == 0 ? wt : (grp == 1 ? wp : wg);
        const float* gg = grp == 0 ? g1 : (grp == 1 ? g2 : g3);
        const float* bb = grp == 0 ? b1 : (grp == 1 ? b2 : b3);
        const float* mm = grp == 0 ? m1 : (grp == 1 ? m2 : m3);
        const float* vv = grp == 0 ? v1 : (grp == 1 ? v2 : v3);
        float scale = gg[ch] * rsqrtf(vv[ch] + BN_EPS);
        W1bf[id] = f2bf(wsrc[ch * 256 + c] * scale);
        if (c == 0) shift1[r] = bb[ch] - mm[ch] * scale;
    }
    if (id < 256 * 128) {
        int o = id >> 7;
        float scale = g4[o] * rsqrtf(v4[o] + BN_EPS);
        Wzbf[id] = f2bf(wz[id] * scale);
        if ((id & 127) == 0) shift4[o] = b4[o] - m4[o] * scale;
    }
}

// ------------------------------------------------------------ K1 = g1+g2 --
// One 128-pixel subtile per block (grid 32x16 = 512 blocks -> 2 blocks/CU).
// 64 KB LDS pool: GEMM phase = A(48K)+B(16K); then the SAME pool becomes the
// 4 phi/g tiles (64K) for the KV phase (A/B are dead after the last barrier).
// theta -> HBM; KV partial -> partials[n][sk].
// NOTE: launch_bounds 2nd arg behaves as min BLOCKS/CU (CUDA semantics):
// (512,4) capped VGPR at 64 -> catastrophic spill (r6: WRITE_SIZE 347MB).
// (512,2) -> 128-VGPR cap, fits the 128-float accumulator state, 2 blocks/CU.
__global__ __launch_bounds__(512, 2) void k1_kernel(
    const float* __restrict__ x, const u16* __restrict__ W1,
    const float* __restrict__ shift1,
    u16* __restrict__ theta_sm, float* __restrict__ partials)
{
    const int sk = blockIdx.x, n = blockIdx.y;   // sk 0..31
    const int tid = threadIdx.x;
    const int w = tid >> 6, lane = tid & 63;
    const int quad = lane >> 4, l16 = lane & 15;

    __shared__ __align__(16) u16 pool[32768];    // 64 KB
    u16* ldsA = pool;                            // 384*64 (48 KB)
    u16* ldsB = pool + 24576;                    // 128*64 (16 KB)
    // KV phase: tile t at pool + t*8192  (phiL, phiH, gL, gH)

    floatx4 acc[3][8];
#pragma unroll
    for (int i = 0; i < 3; ++i)
#pragma unroll
        for (int j = 0; j < 8; ++j) acc[i][j] = floatx4{0.f, 0.f, 0.f, 0.f};

    const int cp = w * 4 + quad;   // channel pair 0..31
    const float* xb = x + ((size_t)n * 256 + 2 * cp) * 4096 + sk * 128;
    unsigned int* ldsBdw = (unsigned int*)ldsB;

    float4 xv[2][2];               // single prefetch buffer (16 VGPR)

    auto loadx = [&](int kc) {
#pragma unroll
        for (int ch = 0; ch < 2; ++ch)
#pragma unroll
            for (int hb = 0; hb < 2; ++hb)
                xv[ch][hb] = *((const float4*)(xb + (size_t)(kc * 64 + ch) * 4096) + hb * 16 + l16);
    };
    auto writeB = [&]() {
#pragma unroll
        for (int hb = 0; hb < 2; ++hb)
#pragma unroll
            for (int j = 0; j < 4; ++j) {
                int s = hb * 64 + l16 * 4 + j;
                ldsBdw[s * 32 + addsw(w, s) * 4 + quad] =
                    cvtpk(((const float*)&xv[0][hb])[j], ((const float*)&xv[1][hb])[j]);
            }
    };
    auto stageA = [&](int kc) {
#pragma unroll
        for (int i = 0; i < 6; ++i) {
            int op = w * 6 + i;
            int r = op * 8 + (lane >> 3);
            int lseg = (lane & 7) ^ (r & 7);
            gld16(W1 + (size_t)r * 256 + kc * 64 + lseg * 8, ldsA + op * 512);
        }
    };

    loadx(0);
    for (int kc = 0; kc < 4; ++kc) {
        writeB();
        if (kc < 3) loadx(kc + 1);   // refill xv; consumed next iter (post-barrier)
        stageA(kc);
        __syncthreads();
#pragma unroll
        for (int kk = 0; kk < 2; ++kk) {
            bf16x8 a[3];
#pragma unroll
            for (int mt = 0; mt < 3; ++mt) {
                int r = mt * 128 + w * 16 + l16;
                int phys = (kk * 4 + quad) ^ (r & 7);
                a[mt] = *(const bf16x8*)(ldsA + r * 64 + phys * 8);
            }
#pragma unroll
            for (int ni = 0; ni < 8; ++ni) {
                int s = ni * 16 + l16;
                int phys = addsw(kk * 4 + quad, s);
                bf16x8 b = *(const bf16x8*)(ldsB + s * 64 + phys * 8);
#pragma unroll
                for (int mt = 0; mt < 3; ++mt)
                    acc[mt][ni] = __builtin_amdgcn_mfma_f32_16x16x32_bf16(
                        a[mt], b, acc[mt][ni], 0, 0, 0);
            }
        }
        __syncthreads();
    }

    const int ocq = w * 16 + quad * 4;
    // theta -> HBM (s-major [s][c], 8B stores)
    {
        float sh0 = shift1[ocq + 0], sh1 = shift1[ocq + 1];
        float sh2 = shift1[ocq + 2], sh3 = shift1[ocq + 3];
#pragma unroll
        for (int ni = 0; ni < 8; ++ni) {
            int s = sk * 128 + ni * 16 + l16;
            float v0 = acc[0][ni][0] + sh0, v1 = acc[0][ni][1] + sh1;
            float v2 = acc[0][ni][2] + sh2, v3 = acc[0][ni][3] + sh3;
            v0 = v0 > 0.f ? v0 : 0.f;
            v1 = v1 > 0.f ? v1 : 0.f;
            v2 = v2 > 0.f ? v2 : 0.f;
            v3 = v3 > 0.f ? v3 : 0.f;
            uint2 pk;
            pk.x = cvtpk(v0, v1);
            pk.y = cvtpk(v2, v3);
            *(uint2*)(theta_sm + (size_t)n * 524288 + (size_t)s * 128 + ocq) = pk;
        }
    }
    // phi (mt=1) -> tiles 0/1, g (mt=2) -> tiles 2/3 in the pool (A/B dead).
    // Rows [ch][64], xor seg swizzle phys = (s6>>3) ^ (ch&7).
#pragma unroll
    for (int mt = 1; mt < 3; ++mt)
#pragma unroll
        for (int r = 0; r < 4; ++r) {
            int ch = ocq + r;
            float sh = shift1[mt * 128 + ch];
#pragma unroll
            for (int ni = 0; ni < 8; ++ni) {
                int sl = ni * 16 + l16;
                int half = sl >> 6, s6 = sl & 63;
                int phys = (s6 >> 3) ^ (ch & 7);
                float val = acc[mt][ni][r] + sh;
                val = val > 0.f ? val : 0.f;
                pool[((mt - 1) * 2 + half) * 8192 + ch * 64 + phys * 8 + (s6 & 7)] = f2bf(val);
            }
        }
    __syncthreads();

    // KV[d][c] = sum_s g[d,s] * phi[c,s] over this block's 128 pixels
    floatx4 kv[8];
#pragma unroll
    for (int i = 0; i < 8; ++i) kv[i] = floatx4{0.f, 0.f, 0.f, 0.f};
#pragma unroll
    for (int h = 0; h < 2; ++h)
#pragma unroll
        for (int kk = 0; kk < 2; ++kk) {
            int rd = w * 16 + l16;
            int physa = (kk * 4 + quad) ^ (rd & 7);
            bf16x8 a = *(const bf16x8*)(pool + (2 + h) * 8192 + rd * 64 + physa * 8);
#pragma unroll
            for (int ci = 0; ci < 8; ++ci) {
                int rc = ci * 16 + l16;
                int physb = (kk * 4 + quad) ^ (rc & 7);
                bf16x8 b = *(const bf16x8*)(pool + h * 8192 + rc * 64 + physb * 8);
                kv[ci] = __builtin_amdgcn_mfma_f32_16x16x32_bf16(a, b, kv[ci], 0, 0, 0);
            }
        }

    float* outp = partials + (size_t)(n * 32 + sk) * 16384;
#pragma unroll
    for (int r = 0; r < 4; ++r) {
        int d = w * 16 + quad * 4 + r;
#pragma unroll
        for (int ci = 0; ci < 8; ++ci)
            outp[d * 128 + ci * 16 + l16] = kv[ci][r];
    }
}

// ----------------------------------------------------------- kv reduce ----
__global__ __launch_bounds__(256) void kv_reduce_kernel(
    const float* __restrict__ partials, u16* __restrict__ kvT)
{
    int n = blockIdx.y;
    int f4 = blockIdx.x * 256 + threadIdx.x;    // 0..4095
    const float4* p4 = (const float4*)partials;
    float4 s = {0.f, 0.f, 0.f, 0.f};
#pragma unroll
    for (int kc = 0; kc < 32; ++kc) {
        float4 v = p4[(size_t)(n * 32 + kc) * 4096 + f4];
        s.x += v.x; s.y += v.y; s.z += v.z; s.w += v.w;
    }
    u16x4 o; o[0] = f2bf(s.x); o[1] = f2bf(s.y); o[2] = f2bf(s.z); o[3] = f2bf(s.w);
    *(u16x4*)(kvT + (size_t)n * 16384 + f4 * 4) = o;
}

// ------------------------------------------------------------ K34 = g3+g4 -
// y[c2][s2 = st*128+j] = (theta @ kvT^T)[s = c2*32 + st][d = j]  (reshape!)
// 64 KB pool (2 blocks/CU): region A = TK buf0 / Wz chunks; region B = TK
// buf1, then Y[2][128][64].  out[o][st*128+j] = relu(Wz.y + shift4 + x).
__global__ __launch_bounds__(512, 2) void k34_kernel(
    const u16* __restrict__ theta_sm, const u16* __restrict__ kvT,
    const u16* __restrict__ Wz, const float* __restrict__ shift4,
    const float* __restrict__ x, float* __restrict__ out)
{
    const int st = blockIdx.x, n = blockIdx.y;   // st 0..31
    const int tid = threadIdx.x;
    const int w = tid >> 6, lane = tid & 63;
    const int quad = lane >> 4, l16 = lane & 15;

    __shared__ __align__(16) u16 pool[32768];    // 64 KB
    u16* Y = pool + 16384;                       // region B as Y

    // theta row c2 lives at tbase + c2*4096 (s = c2*32 + st)
    const u16* tbase = theta_sm + (size_t)n * 524288 + (size_t)st * 128;
    const u16* kbase = kvT + (size_t)n * 16384;

    floatx4 acc3[8];
#pragma unroll
    for (int i = 0; i < 8; ++i) acc3[i] = floatx4{0.f, 0.f, 0.f, 0.f};

    auto stageTK = [&](u16* T, u16* K, int ch) {
#pragma unroll
        for (int i = 0; i < 2; ++i) {
            int op = w * 2 + i;
            int r = op * 8 + (lane >> 3);       // = c2 for T, = d for K
            int lseg = (lane & 7) ^ (r & 7);
            gld16(tbase + (size_t)r * 4096 + ch * 64 + lseg * 8, T + op * 512);
            gld16(kbase + (size_t)r * 128 + ch * 64 + lseg * 8, K + op * 512);
        }
    };
    auto stageWz = [&](int ch) {                 // 256 o-rows x 64 c2 -> region A
#pragma unroll
        for (int i = 0; i < 4; ++i) {
            int op = w * 4 + i;
            int r = op * 8 + (lane >> 3);
            int lseg = (lane & 7) ^ (r & 7);
            gld16(Wz + (size_t)r * 128 + ch * 64 + lseg * 8, pool + op * 512);
        }
    };
    auto comp3 = [&](const u16* T, const u16* K) {
#pragma unroll
        for (int kk = 0; kk < 2; ++kk) {
            int rc2 = w * 16 + l16;
            int physa = (kk * 4 + quad) ^ (rc2 & 7);
            bf16x8 a = *(const bf16x8*)(T + rc2 * 64 + physa * 8);
#pragma unroll
            for (int di = 0; di < 8; ++di) {
                int rd = di * 16 + l16;
                int physb = (kk * 4 + quad) ^ (rd & 7);
                bf16x8 b = *(const bf16x8*)(K + rd * 64 + physb * 8);
                acc3[di] = __builtin_amdgcn_mfma_f32_16x16x32_bf16(a, b, acc3[di], 0, 0, 0);
            }
        }
    };

    stageTK(pool, pool + 8192, 0);               // TK0 -> region A
    __syncthreads();                             // b0
    stageTK(pool + 16384, pool + 24576, 1);      // TK1 -> region B
    comp3(pool, pool + 8192);
    __syncthreads();                             // b1 (A reads drained)
    stageWz(0);                                  // Wz ch0 -> region A (overlaps comp3 B)
    comp3(pool + 16384, pool + 24576);
    __syncthreads();                             // b2 (B reads + Wz staging drained)

    // acc3[di][r] = y_loc[c2 = w*16+quad*4+r][j = di*16+l16];
    // write TRANSPOSED into Y[half c2][j][c64], phys = (c64>>3)^(j&7).
#pragma unroll
    for (int di = 0; di < 8; ++di) {
        int j = di * 16 + l16;
#pragma unroll
        for (int r = 0; r < 4; ++r) {
            int c2 = w * 16 + quad * 4 + r;
            int half = c2 >> 6, c64 = c2 & 63;
            int phys = (c64 >> 3) ^ (j & 7);
            Y[half * 8192 + j * 64 + phys * 8 + (c64 & 7)] = f2bf(acc3[di][r]);
        }
    }
    __syncthreads();                             // b3 (Y visible)

    floatx4 acc4[2][8];
#pragma unroll
    for (int i = 0; i < 2; ++i)
#pragma unroll
        for (int j = 0; j < 8; ++j) acc4[i][j] = floatx4{0.f, 0.f, 0.f, 0.f};

    auto comp4 = [&](int ch) {                   // Wz chunk in region A
#pragma unroll
        for (int kk = 0; kk < 2; ++kk) {
            bf16x8 a[2];
#pragma unroll
            for (int mi = 0; mi < 2; ++mi) {
                int r = w * 32 + mi * 16 + l16;
                int phys = (kk * 4 + quad) ^ (r & 7);
                a[mi] = *(const bf16x8*)(pool + r * 64 + phys * 8);
            }
#pragma unroll
            for (int ni = 0; ni < 8; ++ni) {
                int s = ni * 16 + l16;          // j
                int phys = (kk * 4 + quad) ^ (s & 7);
                bf16x8 b = *(const bf16x8*)(Y + ch * 8192 + s * 64 + phys * 8);
#pragma unroll
                for (int mi = 0; mi < 2; ++mi)
                    acc4[mi][ni] = __builtin_amdgcn_mfma_f32_16x16x32_bf16(
                        a[mi], b, acc4[mi][ni], 0, 0, 0);
            }
        }
    };

    comp4(0);
    __syncthreads();                             // b4 (A reads drained)
    stageWz(1);
    __syncthreads();                             // b5
    comp4(1);

#pragma unroll
    for (int mi = 0; mi < 2; ++mi)
#pragma unroll
        for (int r = 0; r < 4; ++r) {
            int o = w * 32 + mi * 16 + quad * 4 + r;
            float sh = shift4[o];
#pragma unroll
            for (int ni = 0; ni < 8; ++ni) {
                int s2 = st * 128 + ni * 16 + l16;
                size_t idx = ((size_t)n * 256 + o) * 4096 + s2;
                float val = acc4[mi][ni][r] + sh + x[idx];
                out[idx] = val > 0.f ? val : 0.f;
            }
        }
}

// -------------------------------------------------------------- launch ----
extern "C" void kernel_launch(void* const* d_in, const int* in_sizes, int n_in,
                              void* d_out, int out_size, void* d_ws, size_t ws_size,
                              hipStream_t stream)
{
    const float* x  = (const float*)d_in[0];
    const float* wt = (const float*)d_in[1];
    const float* wp = (const float*)d_in[2];
    const float* wg = (const float*)d_in[3];
    const float* wz = (const float*)d_in[4];
    const float* bn[16];
    for (int i = 0; i < 16; ++i) bn[i] = (const float*)d_in[5 + i];

    char* ws = (char*)d_ws;
    u16*   W1bf     = (u16*)  (ws + 0);          // 196608
    float* shift1   = (float*)(ws + 196608);     // 1536
    u16*   Wzbf     = (u16*)  (ws + 198144);     // 65536
    float* shift4   = (float*)(ws + 263680);     // 1024
    u16*   theta_sm = (u16*)  (ws + 264704);     // 16*4096*128*2 = 16777216
    float* partials = (float*)(ws + 17041920);   // 16*32*16384*4 = 33554432
    u16*   kvT      = (u16*)  (ws + 50596352);   // 524288 (end ~51.1 MB)
    float* out = (float*)d_out;

    prep_kernel<<<384, 256, 0, stream>>>(
        wt, wp, wg, wz,
        bn[0], bn[1], bn[2], bn[3],
        bn[4], bn[5], bn[6], bn[7],
        bn[8], bn[9], bn[10], bn[11],
        bn[12], bn[13], bn[14], bn[15],
        W1bf, shift1, Wzbf, shift4);

    k1_kernel<<<dim3(32, 16), 512, 0, stream>>>(x, W1bf, shift1, theta_sm, partials);
    kv_reduce_kernel<<<dim3(16, 16), 256, 0, stream>>>(partials, kvT);
    k34_kernel<<<dim3(32, 16), 512, 0, stream>>>(theta_sm, kvT, Wzbf, shift4, x, out);
}

// Round 8
// 193.908 us; speedup vs baseline: 1.6214x; 1.0247x over previous
//
#include <hip/hip_runtime.h>

#define BN_EPS 1e-5f

typedef unsigned short u16;
typedef __bf16 bf16x8 __attribute__((ext_vector_type(8)));
typedef float floatx4 __attribute__((ext_vector_type(4)));
typedef u16 u16x4 __attribute__((ext_vector_type(4)));
typedef u16 u16x8 __attribute__((ext_vector_type(8)));

__device__ __forceinline__ u16 f2bf(float f) {
    union { float f; unsigned int u; } v; v.f = f;
    unsigned int r = (v.u + 0x7fffu + ((v.u >> 16) & 1u)) >> 16;
    return (u16)r;
}

__device__ __forceinline__ float bf2f(u16 b) {
    union { unsigned int u; float f; } v; v.u = ((unsigned int)b) << 16;
    return v.f;
}

// packed f32x2 -> bf16x2 (RNE), one VALU op
__device__ __forceinline__ unsigned int cvtpk(float lo, float hi) {
    unsigned int r;
    asm("v_cvt_pk_bf16_f32 %0, %1, %2" : "=v"(r) : "v"(lo), "v"(hi));
    return r;
}

// async 16B global->LDS; lane i lands at (wave-uniform) dst + i*16.
__device__ __forceinline__ void gld16(const void* gsrc, void* ldst) {
    __builtin_amdgcn_global_load_lds(
        (const __attribute__((address_space(1))) unsigned int*)gsrc,
        (__attribute__((address_space(3))) unsigned int*)ldst, 16, 0, 0);
}

// additive seg swizzle for transpose-staged [row][64] u16 tiles
__device__ __forceinline__ int addsw(int seg, int s) {
    return (seg + (s & 7) + ((s >> 3) & 7)) & 7;
}

// ---------------------------------------------------------------- prep ----
__global__ __launch_bounds__(256) void prep_kernel(
    const float* __restrict__ wt, const float* __restrict__ wp,
    const float* __restrict__ wg, const float* __restrict__ wz,
    const float* __restrict__ g1, const float* __restrict__ b1,
    const float* __restrict__ m1, const float* __restrict__ v1,
    const float* __restrict__ g2, const float* __restrict__ b2,
    const float* __restrict__ m2, const float* __restrict__ v2,
    const float* __restrict__ g3, const float* __restrict__ b3,
    const float* __restrict__ m3, const float* __restrict__ v3,
    const float* __restrict__ g4, const float* __restrict__ b4,
    const float* __restrict__ m4, const float* __restrict__ v4,
    u16* __restrict__ W1bf, float* __restrict__ shift1,
    u16* __restrict__ Wzbf, float* __restrict__ shift4)
{
    int id = blockIdx.x * 256 + threadIdx.x;
    if (id < 384 * 256) {
        int r = id >> 8, c = id & 255;
        int grp = r >> 7, ch = r & 127;
        const float* wsrc = grp == 0 ? wt : (grp == 1 ? wp : wg);
        const float* gg = grp == 0 ? g1 : (grp == 1 ? g2 : g3);
        const float* bb = grp == 0 ? b1 : (grp == 1 ? b2 : b3);
        const float* mm = grp == 0 ? m1 : (grp == 1 ? m2 : m3);
        const float* vv = grp == 0 ? v1 : (grp == 1 ? v2 : v3);
        float scale = gg[ch] * rsqrtf(vv[ch] + BN_EPS);
        W1bf[id] = f2bf(wsrc[ch * 256 + c] * scale);
        if (c == 0) shift1[r] = bb[ch] - mm[ch] * scale;
    }
    if (id < 256 * 128) {
        int o = id >> 7;
        float scale = g4[o] * rsqrtf(v4[o] + BN_EPS);
        Wzbf[id] = f2bf(wz[id] * scale);
        if ((id & 127) == 0) shift4[o] = b4[o] - m4[o] * scale;
    }
}

// ------------------------------------------------------------ K1 = g1+g2 --
// One 128-pixel subtile per block (grid 32x16 = 512 blocks -> 2 blocks/CU).
// 64 KB LDS pool: GEMM phase = A(48K)+B(16K); then the SAME pool becomes the
// 4 phi/g tiles (64K) for the KV phase.  theta -> HBM (bf16); KV partial ->
// partials[n][sk] in BF16 (halves split-K traffic vs f32).
// x-loads ping-pong 2 phases ahead (xva/xvb) to cover HBM latency.
// launch_bounds 2nd arg = min BLOCKS/CU (CUDA semantics): (512,2) -> 128-VGPR
// cap; acc overflow lands in AGPRs (round-2 precedent: VGPR 104, no spill).
__global__ __launch_bounds__(512, 2) void k1_kernel(
    const float* __restrict__ x, const u16* __restrict__ W1,
    const float* __restrict__ shift1,
    u16* __restrict__ theta_sm, u16* __restrict__ partials)
{
    const int sk = blockIdx.x, n = blockIdx.y;   // sk 0..31
    const int tid = threadIdx.x;
    const int w = tid >> 6, lane = tid & 63;
    const int quad = lane >> 4, l16 = lane & 15;

    __shared__ __align__(16) u16 pool[32768];    // 64 KB
    u16* ldsA = pool;                            // 384*64 (48 KB)
    u16* ldsB = pool + 24576;                    // 128*64 (16 KB)
    // KV phase: tile t at pool + t*8192  (phiL, phiH, gL, gH)

    floatx4 acc[3][8];
#pragma unroll
    for (int i = 0; i < 3; ++i)
#pragma unroll
        for (int j = 0; j < 8; ++j) acc[i][j] = floatx4{0.f, 0.f, 0.f, 0.f};

    const int cp = w * 4 + quad;   // channel pair 0..31
    const float* xb = x + ((size_t)n * 256 + 2 * cp) * 4096 + sk * 128;
    unsigned int* ldsBdw = (unsigned int*)ldsB;

    float4 xva[2][2], xvb[2][2];   // ping-pong prefetch (2 kc ahead)

    auto loadx = [&](float4 (&xv)[2][2], int kc) {
#pragma unroll
        for (int ch = 0; ch < 2; ++ch)
#pragma unroll
            for (int hb = 0; hb < 2; ++hb)
                xv[ch][hb] = *((const float4*)(xb + (size_t)(kc * 64 + ch) * 4096) + hb * 16 + l16);
    };
    auto writeB = [&](const float4 (&xv)[2][2]) {
#pragma unroll
        for (int hb = 0; hb < 2; ++hb)
#pragma unroll
            for (int j = 0; j < 4; ++j) {
                int s = hb * 64 + l16 * 4 + j;
                ldsBdw[s * 32 + addsw(w, s) * 4 + quad] =
                    cvtpk(((const float*)&xv[0][hb])[j], ((const float*)&xv[1][hb])[j]);
            }
    };
    auto stageA = [&](int kc) {
#pragma unroll
        for (int i = 0; i < 6; ++i) {
            int op = w * 6 + i;
            int r = op * 8 + (lane >> 3);
            int lseg = (lane & 7) ^ (r & 7);
            gld16(W1 + (size_t)r * 256 + kc * 64 + lseg * 8, ldsA + op * 512);
        }
    };
    auto compute = [&]() {
#pragma unroll
        for (int kk = 0; kk < 2; ++kk) {
            bf16x8 a[3];
#pragma unroll
            for (int mt = 0; mt < 3; ++mt) {
                int r = mt * 128 + w * 16 + l16;
                int phys = (kk * 4 + quad) ^ (r & 7);
                a[mt] = *(const bf16x8*)(ldsA + r * 64 + phys * 8);
            }
#pragma unroll
            for (int ni = 0; ni < 8; ++ni) {
                int s = ni * 16 + l16;
                int phys = addsw(kk * 4 + quad, s);
                bf16x8 b = *(const bf16x8*)(ldsB + s * 64 + phys * 8);
#pragma unroll
                for (int mt = 0; mt < 3; ++mt)
                    acc[mt][ni] = __builtin_amdgcn_mfma_f32_16x16x32_bf16(
                        a[mt], b, acc[mt][ni], 0, 0, 0);
            }
        }
    };

    loadx(xva, 0);
    loadx(xvb, 1);
    // kc=0
    writeB(xva); loadx(xva, 2); stageA(0);
    __syncthreads(); compute(); __syncthreads();
    // kc=1
    writeB(xvb); loadx(xvb, 3); stageA(1);
    __syncthreads(); compute(); __syncthreads();
    // kc=2
    writeB(xva); stageA(2);
    __syncthreads(); compute(); __syncthreads();
    // kc=3
    writeB(xvb); stageA(3);
    __syncthreads(); compute(); __syncthreads();

    const int ocq = w * 16 + quad * 4;
    // theta -> HBM (s-major [s][c], 8B stores)
    {
        float sh0 = shift1[ocq + 0], sh1 = shift1[ocq + 1];
        float sh2 = shift1[ocq + 2], sh3 = shift1[ocq + 3];
#pragma unroll
        for (int ni = 0; ni < 8; ++ni) {
            int s = sk * 128 + ni * 16 + l16;
            float v0 = acc[0][ni][0] + sh0, v1 = acc[0][ni][1] + sh1;
            float v2 = acc[0][ni][2] + sh2, v3 = acc[0][ni][3] + sh3;
            v0 = v0 > 0.f ? v0 : 0.f;
            v1 = v1 > 0.f ? v1 : 0.f;
            v2 = v2 > 0.f ? v2 : 0.f;
            v3 = v3 > 0.f ? v3 : 0.f;
            uint2 pk;
            pk.x = cvtpk(v0, v1);
            pk.y = cvtpk(v2, v3);
            *(uint2*)(theta_sm + (size_t)n * 524288 + (size_t)s * 128 + ocq) = pk;
        }
    }
    // phi (mt=1) -> tiles 0/1, g (mt=2) -> tiles 2/3 in the pool (A/B dead).
    // Rows [ch][64], xor seg swizzle phys = (s6>>3) ^ (ch&7).
#pragma unroll
    for (int mt = 1; mt < 3; ++mt)
#pragma unroll
        for (int r = 0; r < 4; ++r) {
            int ch = ocq + r;
            float sh = shift1[mt * 128 + ch];
#pragma unroll
            for (int ni = 0; ni < 8; ++ni) {
                int sl = ni * 16 + l16;
                int half = sl >> 6, s6 = sl & 63;
                int phys = (s6 >> 3) ^ (ch & 7);
                float val = acc[mt][ni][r] + sh;
                val = val > 0.f ? val : 0.f;
                pool[((mt - 1) * 2 + half) * 8192 + ch * 64 + phys * 8 + (s6 & 7)] = f2bf(val);
            }
        }
    __syncthreads();

    // KV[d][c] = sum_s g[d,s] * phi[c,s] over this block's 128 pixels
    floatx4 kv[8];
#pragma unroll
    for (int i = 0; i < 8; ++i) kv[i] = floatx4{0.f, 0.f, 0.f, 0.f};
#pragma unroll
    for (int h = 0; h < 2; ++h)
#pragma unroll
        for (int kk = 0; kk < 2; ++kk) {
            int rd = w * 16 + l16;
            int physa = (kk * 4 + quad) ^ (rd & 7);
            bf16x8 a = *(const bf16x8*)(pool + (2 + h) * 8192 + rd * 64 + physa * 8);
#pragma unroll
            for (int ci = 0; ci < 8; ++ci) {
                int rc = ci * 16 + l16;
                int physb = (kk * 4 + quad) ^ (rc & 7);
                bf16x8 b = *(const bf16x8*)(pool + h * 8192 + rc * 64 + physb * 8);
                kv[ci] = __builtin_amdgcn_mfma_f32_16x16x32_bf16(a, b, kv[ci], 0, 0, 0);
            }
        }

    // partials in BF16: halves the split-K round-trip traffic
    u16* outp = partials + (size_t)(n * 32 + sk) * 16384;
#pragma unroll
    for (int r = 0; r < 4; ++r) {
        int d = w * 16 + quad * 4 + r;
#pragma unroll
        for (int ci = 0; ci < 8; ++ci)
            outp[d * 128 + ci * 16 + l16] = f2bf(kv[ci][r]);
    }
}

// ----------------------------------------------------------- kv reduce ----
// Sums 32 bf16 partials per n in f32, writes bf16 kvT.
__global__ __launch_bounds__(256) void kv_reduce_kernel(
    const u16* __restrict__ partials, u16* __restrict__ kvT)
{
    int n = blockIdx.y;
    int f4 = blockIdx.x * 256 + threadIdx.x;    // 0..4095 (4 elems each)
    float s0 = 0.f, s1 = 0.f, s2 = 0.f, s3 = 0.f;
#pragma unroll
    for (int kc = 0; kc < 32; ++kc) {
        u16x4 v = *(const u16x4*)(partials + (size_t)(n * 32 + kc) * 16384 + f4 * 4);
        s0 += bf2f(v[0]); s1 += bf2f(v[1]); s2 += bf2f(v[2]); s3 += bf2f(v[3]);
    }
    u16x4 o; o[0] = f2bf(s0); o[1] = f2bf(s1); o[2] = f2bf(s2); o[3] = f2bf(s3);
    *(u16x4*)(kvT + (size_t)n * 16384 + f4 * 4) = o;
}

// ------------------------------------------------------------ K34 = g3+g4 -
// y[c2][s2 = st*128+j] = (theta @ kvT^T)[s = c2*32 + st][d = j]  (reshape!)
// 64 KB pool (2 blocks/CU): region A = TK buf0 / Wz chunks; region B = TK
// buf1, then Y[2][128][64].  out[o][st*128+j] = relu(Wz.y + shift4 + x).
__global__ __launch_bounds__(512, 2) void k34_kernel(
    const u16* __restrict__ theta_sm, const u16* __restrict__ kvT,
    const u16* __restrict__ Wz, const float* __restrict__ shift4,
    const float* __restrict__ x, float* __restrict__ out)
{
    const int st = blockIdx.x, n = blockIdx.y;   // st 0..31
    const int tid = threadIdx.x;
    const int w = tid >> 6, lane = tid & 63;
    const int quad = lane >> 4, l16 = lane & 15;

    __shared__ __align__(16) u16 pool[32768];    // 64 KB
    u16* Y = pool + 16384;                       // region B as Y

    // theta row c2 lives at tbase + c2*4096 (s = c2*32 + st)
    const u16* tbase = theta_sm + (size_t)n * 524288 + (size_t)st * 128;
    const u16* kbase = kvT + (size_t)n * 16384;

    floatx4 acc3[8];
#pragma unroll
    for (int i = 0; i < 8; ++i) acc3[i] = floatx4{0.f, 0.f, 0.f, 0.f};

    auto stageTK = [&](u16* T, u16* K, int ch) {
#pragma unroll
        for (int i = 0; i < 2; ++i) {
            int op = w * 2 + i;
            int r = op * 8 + (lane >> 3);       // = c2 for T, = d for K
            int lseg = (lane & 7) ^ (r & 7);
            gld16(tbase + (size_t)r * 4096 + ch * 64 + lseg * 8, T + op * 512);
            gld16(kbase + (size_t)r * 128 + ch * 64 + lseg * 8, K + op * 512);
        }
    };
    auto stageWz = [&](int ch) {                 // 256 o-rows x 64 c2 -> region A
#pragma unroll
        for (int i = 0; i < 4; ++i) {
            int op = w * 4 + i;
            int r = op * 8 + (lane >> 3);
            int lseg = (lane & 7) ^ (r & 7);
            gld16(Wz + (size_t)r * 128 + ch * 64 + lseg * 8, pool + op * 512);
        }
    };
    auto comp3 = [&](const u16* T, const u16* K) {
#pragma unroll
        for (int kk = 0; kk < 2; ++kk) {
            int rc2 = w * 16 + l16;
            int physa = (kk * 4 + quad) ^ (rc2 & 7);
            bf16x8 a = *(const bf16x8*)(T + rc2 * 64 + physa * 8);
#pragma unroll
            for (int di = 0; di < 8; ++di) {
                int rd = di * 16 + l16;
                int physb = (kk * 4 + quad) ^ (rd & 7);
                bf16x8 b = *(const bf16x8*)(K + rd * 64 + physb * 8);
                acc3[di] = __builtin_amdgcn_mfma_f32_16x16x32_bf16(a, b, acc3[di], 0, 0, 0);
            }
        }
    };

    stageTK(pool, pool + 8192, 0);               // TK0 -> region A
    __syncthreads();                             // b0
    stageTK(pool + 16384, pool + 24576, 1);      // TK1 -> region B
    comp3(pool, pool + 8192);
    __syncthreads();                             // b1 (A reads drained)
    stageWz(0);                                  // Wz ch0 -> region A (overlaps comp3 B)
    comp3(pool + 16384, pool + 24576);
    __syncthreads();                             // b2 (B reads + Wz staging drained)

    // acc3[di][r] = y_loc[c2 = w*16+quad*4+r][j = di*16+l16];
    // write TRANSPOSED into Y[half c2][j][c64], phys = (c64>>3)^(j&7).
#pragma unroll
    for (int di = 0; di < 8; ++di) {
        int j = di * 16 + l16;
#pragma unroll
        for (int r = 0; r < 4; ++r) {
            int c2 = w * 16 + quad * 4 + r;
            int half = c2 >> 6, c64 = c2 & 63;
            int phys = (c64 >> 3) ^ (j & 7);
            Y[half * 8192 + j * 64 + phys * 8 + (c64 & 7)] = f2bf(acc3[di][r]);
        }
    }
    __syncthreads();                             // b3 (Y visible)

    floatx4 acc4[2][8];
#pragma unroll
    for (int i = 0; i < 2; ++i)
#pragma unroll
        for (int j = 0; j < 8; ++j) acc4[i][j] = floatx4{0.f, 0.f, 0.f, 0.f};

    auto comp4 = [&](int ch) {                   // Wz chunk in region A
#pragma unroll
        for (int kk = 0; kk < 2; ++kk) {
            bf16x8 a[2];
#pragma unroll
            for (int mi = 0; mi < 2; ++mi) {
                int r = w * 32 + mi * 16 + l16;
                int phys = (kk * 4 + quad) ^ (r & 7);
                a[mi] = *(const bf16x8*)(pool + r * 64 + phys * 8);
            }
#pragma unroll
            for (int ni = 0; ni < 8; ++ni) {
                int s = ni * 16 + l16;          // j
                int phys = (kk * 4 + quad) ^ (s & 7);
                bf16x8 b = *(const bf16x8*)(Y + ch * 8192 + s * 64 + phys * 8);
#pragma unroll
                for (int mi = 0; mi < 2; ++mi)
                    acc4[mi][ni] = __builtin_amdgcn_mfma_f32_16x16x32_bf16(
                        a[mi], b, acc4[mi][ni], 0, 0, 0);
            }
        }
    };

    comp4(0);
    __syncthreads();                             // b4 (A reads drained)
    stageWz(1);
    __syncthreads();                             // b5
    comp4(1);

#pragma unroll
    for (int mi = 0; mi < 2; ++mi)
#pragma unroll
        for (int r = 0; r < 4; ++r) {
            int o = w * 32 + mi * 16 + quad * 4 + r;
            float sh = shift4[o];
#pragma unroll
            for (int ni = 0; ni < 8; ++ni) {
                int s2 = st * 128 + ni * 16 + l16;
                size_t idx = ((size_t)n * 256 + o) * 4096 + s2;
                float val = acc4[mi][ni][r] + sh + x[idx];
                out[idx] = val > 0.f ? val : 0.f;
            }
        }
}

// -------------------------------------------------------------- launch ----
extern "C" void kernel_launch(void* const* d_in, const int* in_sizes, int n_in,
                              void* d_out, int out_size, void* d_ws, size_t ws_size,
                              hipStream_t stream)
{
    const float* x  = (const float*)d_in[0];
    const float* wt = (const float*)d_in[1];
    const float* wp = (const float*)d_in[2];
    const float* wg = (const float*)d_in[3];
    const float* wz = (const float*)d_in[4];
    const float* bn[16];
    for (int i = 0; i < 16; ++i) bn[i] = (const float*)d_in[5 + i];

    char* ws = (char*)d_ws;
    u16*   W1bf     = (u16*)  (ws + 0);          // 196608
    float* shift1   = (float*)(ws + 196608);     // 1536
    u16*   Wzbf     = (u16*)  (ws + 198144);     // 65536
    float* shift4   = (float*)(ws + 263680);     // 1024
    u16*   theta_sm = (u16*)  (ws + 264704);     // 16*4096*128*2 = 16777216
    u16*   partials = (u16*)  (ws + 17041920);   // 16*32*16384*2 = 16777216
    u16*   kvT      = (u16*)  (ws + 33819136);   // 524288 (end ~34.3 MB)
    float* out = (float*)d_out;

    prep_kernel<<<384, 256, 0, stream>>>(
        wt, wp, wg, wz,
        bn[0], bn[1], bn[2], bn[3],
        bn[4], bn[5], bn[6], bn[7],
        bn[8], bn[9], bn[10], bn[11],
        bn[12], bn[13], bn[14], bn[15],
        W1bf, shift1, Wzbf, shift4);

    k1_kernel<<<dim3(32, 16), 512, 0, stream>>>(x, W1bf, shift1, theta_sm, partials);
    kv_reduce_kernel<<<dim3(16, 16), 256, 0, stream>>>(partials, kvT);
    k34_kernel<<<dim3(32, 16), 512, 0, stream>>>(theta_sm, kvT, Wzbf, shift4, x, out);
}

// Round 9
// 193.769 us; speedup vs baseline: 1.6225x; 1.0007x over previous
//
#include <hip/hip_runtime.h>

#define BN_EPS 1e-5f

typedef unsigned short u16;
typedef __bf16 bf16x8 __attribute__((ext_vector_type(8)));
typedef float floatx4 __attribute__((ext_vector_type(4)));
typedef u16 u16x4 __attribute__((ext_vector_type(4)));
typedef u16 u16x8 __attribute__((ext_vector_type(8)));

__device__ __forceinline__ u16 f2bf(float f) {
    union { float f; unsigned int u; } v; v.f = f;
    unsigned int r = (v.u + 0x7fffu + ((v.u >> 16) & 1u)) >> 16;
    return (u16)r;
}

__device__ __forceinline__ float bf2f(u16 b) {
    union { unsigned int u; float f; } v; v.u = ((unsigned int)b) << 16;
    return v.f;
}

// packed f32x2 -> bf16x2 (RNE), one VALU op
__device__ __forceinline__ unsigned int cvtpk(float lo, float hi) {
    unsigned int r;
    asm("v_cvt_pk_bf16_f32 %0, %1, %2" : "=v"(r) : "v"(lo), "v"(hi));
    return r;
}

// async 16B global->LDS; lane i lands at (wave-uniform) dst + i*16.
__device__ __forceinline__ void gld16(const void* gsrc, void* ldst) {
    __builtin_amdgcn_global_load_lds(
        (const __attribute__((address_space(1))) unsigned int*)gsrc,
        (__attribute__((address_space(3))) unsigned int*)ldst, 16, 0, 0);
}

// additive seg swizzle for transpose-staged [row][64] u16 tiles
__device__ __forceinline__ int addsw(int seg, int s) {
    return (seg + (s & 7) + ((s >> 3) & 7)) & 7;
}

// ---------------------------------------------------------------- prep ----
__global__ __launch_bounds__(256) void prep_kernel(
    const float* __restrict__ wt, const float* __restrict__ wp,
    const float* __restrict__ wg, const float* __restrict__ wz,
    const float* __restrict__ g1, const float* __restrict__ b1,
    const float* __restrict__ m1, const float* __restrict__ v1,
    const float* __restrict__ g2, const float* __restrict__ b2,
    const float* __restrict__ m2, const float* __restrict__ v2,
    const float* __restrict__ g3, const float* __restrict__ b3,
    const float* __restrict__ m3, const float* __restrict__ v3,
    const float* __restrict__ g4, const float* __restrict__ b4,
    const float* __restrict__ m4, const float* __restrict__ v4,
    u16* __restrict__ W1bf, float* __restrict__ shift1,
    u16* __restrict__ Wzbf, float* __restrict__ shift4)
{
    int id = blockIdx.x * 256 + threadIdx.x;
    if (id < 384 * 256) {
        int r = id >> 8, c = id & 255;
        int grp = r >> 7, ch = r & 127;
        const float* wsrc = grp == 0 ? wt : (grp == 1 ? wp : wg);
        const float* gg = grp == 0 ? g1 : (grp == 1 ? g2 : g3);
        const float* bb = grp == 0 ? b1 : (grp == 1 ? b2 : b3);
        const float* mm = grp == 0 ? m1 : (grp == 1 ? m2 : m3);
        const float* vv = grp == 0 ? v1 : (grp == 1 ? v2 : v3);
        float scale = gg[ch] * rsqrtf(vv[ch] + BN_EPS);
        W1bf[id] = f2bf(wsrc[ch * 256 + c] * scale);
        if (c == 0) shift1[r] = bb[ch] - mm[ch] * scale;
    }
    if (id < 256 * 128) {
        int o = id >> 7;
        float scale = g4[o] * rsqrtf(v4[o] + BN_EPS);
        Wzbf[id] = f2bf(wz[id] * scale);
        if ((id & 127) == 0) shift4[o] = b4[o] - m4[o] * scale;
    }
}

// ------------------------------------------------------------ K1 = g1+g2 --
// One 128-pixel subtile per block (grid 32x16 = 512 blocks -> 2 blocks/CU).
// 64 KB LDS pool: GEMM phase = A(48K)+B(16K); then the SAME pool becomes the
// 4 phi/g tiles (64K) for the KV phase.  theta -> HBM (bf16); KV partial ->
// partials[n][sk] in BF16.
// Single-buffer x prefetch (r7 schedule): the pre-barrier vmcnt(0) drain
// force-completes ALL outstanding loads anyway, so a 2-phase ping-pong adds
// register pressure for zero latency cover (r8: 42->50us regression).
// launch_bounds 2nd arg = min BLOCKS/CU: (512,2) -> 128-VGPR cap, no spill.
__global__ __launch_bounds__(512, 2) void k1_kernel(
    const float* __restrict__ x, const u16* __restrict__ W1,
    const float* __restrict__ shift1,
    u16* __restrict__ theta_sm, u16* __restrict__ partials)
{
    const int sk = blockIdx.x, n = blockIdx.y;   // sk 0..31
    const int tid = threadIdx.x;
    const int w = tid >> 6, lane = tid & 63;
    const int quad = lane >> 4, l16 = lane & 15;

    __shared__ __align__(16) u16 pool[32768];    // 64 KB
    u16* ldsA = pool;                            // 384*64 (48 KB)
    u16* ldsB = pool + 24576;                    // 128*64 (16 KB)
    // KV phase: tile t at pool + t*8192  (phiL, phiH, gL, gH)

    floatx4 acc[3][8];
#pragma unroll
    for (int i = 0; i < 3; ++i)
#pragma unroll
        for (int j = 0; j < 8; ++j) acc[i][j] = floatx4{0.f, 0.f, 0.f, 0.f};

    const int cp = w * 4 + quad;   // channel pair 0..31
    const float* xb = x + ((size_t)n * 256 + 2 * cp) * 4096 + sk * 128;
    unsigned int* ldsBdw = (unsigned int*)ldsB;

    float4 xv[2][2];               // single prefetch buffer (16 VGPR)

    auto loadx = [&](int kc) {
#pragma unroll
        for (int ch = 0; ch < 2; ++ch)
#pragma unroll
            for (int hb = 0; hb < 2; ++hb)
                xv[ch][hb] = *((const float4*)(xb + (size_t)(kc * 64 + ch) * 4096) + hb * 16 + l16);
    };
    auto writeB = [&]() {
#pragma unroll
        for (int hb = 0; hb < 2; ++hb)
#pragma unroll
            for (int j = 0; j < 4; ++j) {
                int s = hb * 64 + l16 * 4 + j;
                ldsBdw[s * 32 + addsw(w, s) * 4 + quad] =
                    cvtpk(((const float*)&xv[0][hb])[j], ((const float*)&xv[1][hb])[j]);
            }
    };
    auto stageA = [&](int kc) {
#pragma unroll
        for (int i = 0; i < 6; ++i) {
            int op = w * 6 + i;
            int r = op * 8 + (lane >> 3);
            int lseg = (lane & 7) ^ (r & 7);
            gld16(W1 + (size_t)r * 256 + kc * 64 + lseg * 8, ldsA + op * 512);
        }
    };

    loadx(0);
    for (int kc = 0; kc < 4; ++kc) {
        writeB();
        if (kc < 3) loadx(kc + 1);   // refill xv; consumed next iter (post-barrier)
        stageA(kc);
        __syncthreads();
#pragma unroll
        for (int kk = 0; kk < 2; ++kk) {
            bf16x8 a[3];
#pragma unroll
            for (int mt = 0; mt < 3; ++mt) {
                int r = mt * 128 + w * 16 + l16;
                int phys = (kk * 4 + quad) ^ (r & 7);
                a[mt] = *(const bf16x8*)(ldsA + r * 64 + phys * 8);
            }
#pragma unroll
            for (int ni = 0; ni < 8; ++ni) {
                int s = ni * 16 + l16;
                int phys = addsw(kk * 4 + quad, s);
                bf16x8 b = *(const bf16x8*)(ldsB + s * 64 + phys * 8);
#pragma unroll
                for (int mt = 0; mt < 3; ++mt)
                    acc[mt][ni] = __builtin_amdgcn_mfma_f32_16x16x32_bf16(
                        a[mt], b, acc[mt][ni], 0, 0, 0);
            }
        }
        __syncthreads();
    }

    const int ocq = w * 16 + quad * 4;
    // theta -> HBM (s-major [s][c], 8B stores)
    {
        float sh0 = shift1[ocq + 0], sh1 = shift1[ocq + 1];
        float sh2 = shift1[ocq + 2], sh3 = shift1[ocq + 3];
#pragma unroll
        for (int ni = 0; ni < 8; ++ni) {
            int s = sk * 128 + ni * 16 + l16;
            float v0 = acc[0][ni][0] + sh0, v1 = acc[0][ni][1] + sh1;
            float v2 = acc[0][ni][2] + sh2, v3 = acc[0][ni][3] + sh3;
            v0 = v0 > 0.f ? v0 : 0.f;
            v1 = v1 > 0.f ? v1 : 0.f;
            v2 = v2 > 0.f ? v2 : 0.f;
            v3 = v3 > 0.f ? v3 : 0.f;
            uint2 pk;
            pk.x = cvtpk(v0, v1);
            pk.y = cvtpk(v2, v3);
            *(uint2*)(theta_sm + (size_t)n * 524288 + (size_t)s * 128 + ocq) = pk;
        }
    }
    // phi (mt=1) -> tiles 0/1, g (mt=2) -> tiles 2/3 in the pool (A/B dead).
    // Rows [ch][64], xor seg swizzle phys = (s6>>3) ^ (ch&7).
#pragma unroll
    for (int mt = 1; mt < 3; ++mt)
#pragma unroll
        for (int r = 0; r < 4; ++r) {
            int ch = ocq + r;
            float sh = shift1[mt * 128 + ch];
#pragma unroll
            for (int ni = 0; ni < 8; ++ni) {
                int sl = ni * 16 + l16;
                int half = sl >> 6, s6 = sl & 63;
                int phys = (s6 >> 3) ^ (ch & 7);
                float val = acc[mt][ni][r] + sh;
                val = val > 0.f ? val : 0.f;
                pool[((mt - 1) * 2 + half) * 8192 + ch * 64 + phys * 8 + (s6 & 7)] = f2bf(val);
            }
        }
    __syncthreads();

    // KV[d][c] = sum_s g[d,s] * phi[c,s] over this block's 128 pixels
    floatx4 kv[8];
#pragma unroll
    for (int i = 0; i < 8; ++i) kv[i] = floatx4{0.f, 0.f, 0.f, 0.f};
#pragma unroll
    for (int h = 0; h < 2; ++h)
#pragma unroll
        for (int kk = 0; kk < 2; ++kk) {
            int rd = w * 16 + l16;
            int physa = (kk * 4 + quad) ^ (rd & 7);
            bf16x8 a = *(const bf16x8*)(pool + (2 + h) * 8192 + rd * 64 + physa * 8);
#pragma unroll
            for (int ci = 0; ci < 8; ++ci) {
                int rc = ci * 16 + l16;
                int physb = (kk * 4 + quad) ^ (rc & 7);
                bf16x8 b = *(const bf16x8*)(pool + h * 8192 + rc * 64 + physb * 8);
                kv[ci] = __builtin_amdgcn_mfma_f32_16x16x32_bf16(a, b, kv[ci], 0, 0, 0);
            }
        }

    // partials in BF16: halves the split-K round-trip traffic
    u16* outp = partials + (size_t)(n * 32 + sk) * 16384;
#pragma unroll
    for (int r = 0; r < 4; ++r) {
        int d = w * 16 + quad * 4 + r;
#pragma unroll
        for (int ci = 0; ci < 8; ++ci)
            outp[d * 128 + ci * 16 + l16] = f2bf(kv[ci][r]);
    }
}

// ----------------------------------------------------------- kv reduce ----
// Sums 32 bf16 partials per n in f32, writes bf16 kvT.
__global__ __launch_bounds__(256) void kv_reduce_kernel(
    const u16* __restrict__ partials, u16* __restrict__ kvT)
{
    int n = blockIdx.y;
    int f4 = blockIdx.x * 256 + threadIdx.x;    // 0..4095 (4 elems each)
    float s0 = 0.f, s1 = 0.f, s2 = 0.f, s3 = 0.f;
#pragma unroll
    for (int kc = 0; kc < 32; ++kc) {
        u16x4 v = *(const u16x4*)(partials + (size_t)(n * 32 + kc) * 16384 + f4 * 4);
        s0 += bf2f(v[0]); s1 += bf2f(v[1]); s2 += bf2f(v[2]); s3 += bf2f(v[3]);
    }
    u16x4 o; o[0] = f2bf(s0); o[1] = f2bf(s1); o[2] = f2bf(s2); o[3] = f2bf(s3);
    *(u16x4*)(kvT + (size_t)n * 16384 + f4 * 4) = o;
}

// ------------------------------------------------------------ K34 = g3+g4 -
// y[c2][s2 = st*128+j] = (theta @ kvT^T)[s = c2*32 + st][d = j]  (reshape!)
// 64 KB pool (2 blocks/CU): region A = TK buf0 / Wz chunks; region B = TK
// buf1, then Y[2][128][64].  out[o][st*128+j] = relu(Wz.y + shift4 + x).
__global__ __launch_bounds__(512, 2) void k34_kernel(
    const u16* __restrict__ theta_sm, const u16* __restrict__ kvT,
    const u16* __restrict__ Wz, const float* __restrict__ shift4,
    const float* __restrict__ x, float* __restrict__ out)
{
    const int st = blockIdx.x, n = blockIdx.y;   // st 0..31
    const int tid = threadIdx.x;
    const int w = tid >> 6, lane = tid & 63;
    const int quad = lane >> 4, l16 = lane & 15;

    __shared__ __align__(16) u16 pool[32768];    // 64 KB
    u16* Y = pool + 16384;                       // region B as Y

    // theta row c2 lives at tbase + c2*4096 (s = c2*32 + st)
    const u16* tbase = theta_sm + (size_t)n * 524288 + (size_t)st * 128;
    const u16* kbase = kvT + (size_t)n * 16384;

    floatx4 acc3[8];
#pragma unroll
    for (int i = 0; i < 8; ++i) acc3[i] = floatx4{0.f, 0.f, 0.f, 0.f};

    auto stageTK = [&](u16* T, u16* K, int ch) {
#pragma unroll
        for (int i = 0; i < 2; ++i) {
            int op = w * 2 + i;
            int r = op * 8 + (lane >> 3);       // = c2 for T, = d for K
            int lseg = (lane & 7) ^ (r & 7);
            gld16(tbase + (size_t)r * 4096 + ch * 64 + lseg * 8, T + op * 512);
            gld16(kbase + (size_t)r * 128 + ch * 64 + lseg * 8, K + op * 512);
        }
    };
    auto stageWz = [&](int ch) {                 // 256 o-rows x 64 c2 -> region A
#pragma unroll
        for (int i = 0; i < 4; ++i) {
            int op = w * 4 + i;
            int r = op * 8 + (lane >> 3);
            int lseg = (lane & 7) ^ (r & 7);
            gld16(Wz + (size_t)r * 128 + ch * 64 + lseg * 8, pool + op * 512);
        }
    };
    auto comp3 = [&](const u16* T, const u16* K) {
#pragma unroll
        for (int kk = 0; kk < 2; ++kk) {
            int rc2 = w * 16 + l16;
            int physa = (kk * 4 + quad) ^ (rc2 & 7);
            bf16x8 a = *(const bf16x8*)(T + rc2 * 64 + physa * 8);
#pragma unroll
            for (int di = 0; di < 8; ++di) {
                int rd = di * 16 + l16;
                int physb = (kk * 4 + quad) ^ (rd & 7);
                bf16x8 b = *(const bf16x8*)(K + rd * 64 + physb * 8);
                acc3[di] = __builtin_amdgcn_mfma_f32_16x16x32_bf16(a, b, acc3[di], 0, 0, 0);
            }
        }
    };

    stageTK(pool, pool + 8192, 0);               // TK0 -> region A
    __syncthreads();                             // b0
    stageTK(pool + 16384, pool + 24576, 1);      // TK1 -> region B
    comp3(pool, pool + 8192);
    __syncthreads();                             // b1 (A reads drained)
    stageWz(0);                                  // Wz ch0 -> region A (overlaps comp3 B)
    comp3(pool + 16384, pool + 24576);
    __syncthreads();                             // b2 (B reads + Wz staging drained)

    // acc3[di][r] = y_loc[c2 = w*16+quad*4+r][j = di*16+l16];
    // write TRANSPOSED into Y[half c2][j][c64], phys = (c64>>3)^(j&7).
#pragma unroll
    for (int di = 0; di < 8; ++di) {
        int j = di * 16 + l16;
#pragma unroll
        for (int r = 0; r < 4; ++r) {
            int c2 = w * 16 + quad * 4 + r;
            int half = c2 >> 6, c64 = c2 & 63;
            int phys = (c64 >> 3) ^ (j & 7);
            Y[half * 8192 + j * 64 + phys * 8 + (c64 & 7)] = f2bf(acc3[di][r]);
        }
    }
    __syncthreads();                             // b3 (Y visible)

    floatx4 acc4[2][8];
#pragma unroll
    for (int i = 0; i < 2; ++i)
#pragma unroll
        for (int j = 0; j < 8; ++j) acc4[i][j] = floatx4{0.f, 0.f, 0.f, 0.f};

    auto comp4 = [&](int ch) {                   // Wz chunk in region A
#pragma unroll
        for (int kk = 0; kk < 2; ++kk) {
            bf16x8 a[2];
#pragma unroll
            for (int mi = 0; mi < 2; ++mi) {
                int r = w * 32 + mi * 16 + l16;
                int phys = (kk * 4 + quad) ^ (r & 7);
                a[mi] = *(const bf16x8*)(pool + r * 64 + phys * 8);
            }
#pragma unroll
            for (int ni = 0; ni < 8; ++ni) {
                int s = ni * 16 + l16;          // j
                int phys = (kk * 4 + quad) ^ (s & 7);
                bf16x8 b = *(const bf16x8*)(Y + ch * 8192 + s * 64 + phys * 8);
#pragma unroll
                for (int mi = 0; mi < 2; ++mi)
                    acc4[mi][ni] = __builtin_amdgcn_mfma_f32_16x16x32_bf16(
                        a[mi], b, acc4[mi][ni], 0, 0, 0);
            }
        }
    };

    comp4(0);
    __syncthreads();                             // b4 (A reads drained)
    stageWz(1);
    __syncthreads();                             // b5
    comp4(1);

#pragma unroll
    for (int mi = 0; mi < 2; ++mi)
#pragma unroll
        for (int r = 0; r < 4; ++r) {
            int o = w * 32 + mi * 16 + quad * 4 + r;
            float sh = shift4[o];
#pragma unroll
            for (int ni = 0; ni < 8; ++ni) {
                int s2 = st * 128 + ni * 16 + l16;
                size_t idx = ((size_t)n * 256 + o) * 4096 + s2;
                float val = acc4[mi][ni][r] + sh + x[idx];
                out[idx] = val > 0.f ? val : 0.f;
            }
        }
}

// -------------------------------------------------------------- launch ----
extern "C" void kernel_launch(void* const* d_in, const int* in_sizes, int n_in,
                              void* d_out, int out_size, void* d_ws, size_t ws_size,
                              hipStream_t stream)
{
    const float* x  = (const float*)d_in[0];
    const float* wt = (const float*)d_in[1];
    const float* wp = (const float*)d_in[2];
    const float* wg = (const float*)d_in[3];
    const float* wz = (const float*)d_in[4];
    const float* bn[16];
    for (int i = 0; i < 16; ++i) bn[i] = (const float*)d_in[5 + i];

    char* ws = (char*)d_ws;
    u16*   W1bf     = (u16*)  (ws + 0);          // 196608
    float* shift1   = (float*)(ws + 196608);     // 1536
    u16*   Wzbf     = (u16*)  (ws + 198144);     // 65536
    float* shift4   = (float*)(ws + 263680);     // 1024
    u16*   theta_sm = (u16*)  (ws + 264704);     // 16*4096*128*2 = 16777216
    u16*   partials = (u16*)  (ws + 17041920);   // 16*32*16384*2 = 16777216
    u16*   kvT      = (u16*)  (ws + 33819136);   // 524288 (end ~34.3 MB)
    float* out = (float*)d_out;

    prep_kernel<<<384, 256, 0, stream>>>(
        wt, wp, wg, wz,
        bn[0], bn[1], bn[2], bn[3],
        bn[4], bn[5], bn[6], bn[7],
        bn[8], bn[9], bn[10], bn[11],
        bn[12], bn[13], bn[14], bn[15],
        W1bf, shift1, Wzbf, shift4);

    k1_kernel<<<dim3(32, 16), 512, 0, stream>>>(x, W1bf, shift1, theta_sm, partials);
    kv_reduce_kernel<<<dim3(16, 16), 256, 0, stream>>>(partials, kvT);
    k34_kernel<<<dim3(32, 16), 512, 0, stream>>>(theta_sm, kvT, Wzbf, shift4, x, out);
}